// Round 9
// baseline (76.051 us; speedup 1.0000x reference)
//
#include <hip/hip_runtime.h>
#include <hip/hip_bf16.h>

#define S_TOT 4096
#define HDIM  1024
#define NH    16
#define DH    64
#define L_    1024
#define NT    19   // 16 local + 3 distinct global tiles (shot-s global == local tile 0, weight 2)

using bf16x8 = __attribute__((ext_vector_type(8))) short;
using f32x16 = __attribute__((ext_vector_type(16))) float;
using i32x4  = __attribute__((ext_vector_type(4))) int;

typedef const __attribute__((address_space(1))) unsigned int* gp1_t;
typedef __attribute__((address_space(3))) unsigned int* lp3_t;

__device__ __forceinline__ short f2bf(float f) {
    union { float f; unsigned u; } x; x.f = f;
    unsigned r = x.u + 0x7FFFu + ((x.u >> 16) & 1u);
    return (short)(r >> 16);
}

__device__ __forceinline__ unsigned cvt_pk_bf16(float lo, float hi) {
    unsigned r;
    asm("v_cvt_pk_bf16_f32 %0, %1, %2" : "=v"(r) : "v"(lo), "v"(hi));
    return r;
}

__device__ __forceinline__ float exp2_fast(float x) {
#if __has_builtin(__builtin_amdgcn_exp2f)
    return __builtin_amdgcn_exp2f(x);
#else
    return exp2f(x);
#endif
}

__device__ __forceinline__ void gload16(const void* g, void* l) {
    __builtin_amdgcn_global_load_lds((gp1_t)g, (lp3_t)(unsigned long)(l), 16, 0, 0);
}

// ---------------- prep: K convert (blocks 0..1023), V transpose (1024..3071) --
__global__ __launch_bounds__(256) void prep_kv(
    const float* __restrict__ kf, const float* __restrict__ vf,
    short* __restrict__ kb, short* __restrict__ vb)
{
    __shared__ short st[64 * 70];
    const int bid = blockIdx.x, tid = threadIdx.x;
    if (bid < 1024) {
        const int gid = bid * 256 + tid;
        #pragma unroll
        for (int it = 0; it < 2; ++it) {
            size_t e = ((size_t)gid + (size_t)it * 262144) * 16;
            #pragma unroll
            for (int half = 0; half < 2; ++half) {
                float4 a = *(const float4*)(kf + e + half * 8);
                float4 c = *(const float4*)(kf + e + half * 8 + 4);
                bf16x8 r;
                r[0]=f2bf(a.x); r[1]=f2bf(a.y); r[2]=f2bf(a.z); r[3]=f2bf(a.w);
                r[4]=f2bf(c.x); r[5]=f2bf(c.y); r[6]=f2bf(c.z); r[7]=f2bf(c.w);
                *(bf16x8*)(kb + e + half * 8) = r;
            }
        }
    } else {
        const int vbid = bid - 1024;
        const int stile = vbid & 63, ht = (vbid >> 6) & 15, b = vbid >> 10;
        const int rt = tid >> 2, q4 = tid & 3;
        const float* src = vf + ((size_t)(b * S_TOT + stile * 64 + rt)) * HDIM + ht * 64 + q4 * 16;
        short* dst = st + rt * 70 + q4 * 16;
        #pragma unroll
        for (int i = 0; i < 4; ++i) {
            float4 x = *(const float4*)(src + i * 4);
            dst[i*4+0] = f2bf(x.x); dst[i*4+1] = f2bf(x.y);
            dst[i*4+2] = f2bf(x.z); dst[i*4+3] = f2bf(x.w);
        }
        __syncthreads();
        const int orow = tid >> 2, oq = tid & 3;
        bf16x8 o0, o1;
        #pragma unroll
        for (int j = 0; j < 8; ++j) o0[j] = st[(oq * 16 + j) * 70 + orow];
        #pragma unroll
        for (int j = 0; j < 8; ++j) o1[j] = st[(oq * 16 + 8 + j) * 70 + orow];
        short* dst2 = vb + ((size_t)((b * NH + ht) * 64 + orow)) * S_TOT + stile * 64 + oq * 16;
        *(bf16x8*)dst2 = o0;
        *(bf16x8*)(dst2 + 8) = o1;
    }
}

// ---------------- attention: R5 per-wave structure, 2-wave blocks, grid 1024 -
// Each block: 2 waves x 64 q rows = 128 q rows; LDS 2 x (K 8KB | V 8KB) = 32KB
// -> 4-5 blocks/CU (independent barrier domains -> cross-block pipe overlap).
__global__ __launch_bounds__(128, 2) void attn_kernel(
    const float* __restrict__ qf, const short* __restrict__ kb,
    const short* __restrict__ vb, float* __restrict__ out)
{
    __shared__ __align__(16) char smem[32768];
    const int tid  = threadIdx.x;
    const int wave = tid >> 6, lane = tid & 63;
    const int hi   = lane >> 5, q32 = lane & 31;

    // bijective XCD swizzle (1024 % 8 == 0); same-XCD blocks share (b,s) K/V
    const int bidhw = blockIdx.x;
    const int bid = ((bidhw & 7) << 7) | (bidhw >> 3);
    const int qt = bid & 7, h = (bid >> 3) & 15, s = (bid >> 7) & 3, b = bid >> 9;

    // ---- Q B-frags, 2 q-sets of 32 rows (scale*log2e folded in)
    const float CSC = 0.125f * 1.4426950408889634f;
    bf16x8 qv[2][4];
    #pragma unroll
    for (int qs = 0; qs < 2; ++qs) {
        const float* qp = qf + ((size_t)(b*S_TOT + s*L_ + qt*128 + wave*64 + qs*32 + q32)) * HDIM
                             + h * DH + hi * 8;
        #pragma unroll
        for (int d = 0; d < 4; ++d) {
            float4 x0 = *(const float4*)(qp + d * 16);
            float4 x1 = *(const float4*)(qp + d * 16 + 4);
            i32x4 u;
            u[0] = (int)cvt_pk_bf16(x0.x * CSC, x0.y * CSC);
            u[1] = (int)cvt_pk_bf16(x0.z * CSC, x0.w * CSC);
            u[2] = (int)cvt_pk_bf16(x1.x * CSC, x1.y * CSC);
            u[3] = (int)cvt_pk_bf16(x1.z * CSC, x1.w * CSC);
            qv[qs][d] = __builtin_bit_cast(bf16x8, u);
        }
    }

    // ---- staging offsets (chunk swizzle + K row bit2<->3 permute on GLOBAL side,
    // LDS dest linear). Chunk cid = i*128 + tid, i in [0,4): row = i*16 + r_low,
    // r_low = wave*8 + (lane>>3); both swizzle terms are i-invariant -> affine.
    const int r_low = (wave << 3) | (lane >> 3);
    const int lch   = (lane & 7) ^ (lane >> 3);
    const int krow_low = (r_low & 3) | ((r_low & 4) << 1) | ((r_low & 8) >> 1);
    const size_t ko = (size_t)krow_low * 2048 + (lch << 4);
    const size_t vo = (size_t)r_low * 8192 + (lch << 4);
    const char* kbase = (const char*)kb + ((size_t)b * S_TOT) * 2048 + h * 128;
    const char* vbase = (const char*)vb + ((size_t)(b * NH + h)) * (64ull * 8192);

    auto abs_tile_of = [&](int t) -> int {
        if (t < 16) return s * 16 + t;
        int g = t - 16; if (g >= s) ++g;
        return g * 16;
    };
    auto stage = [&](int t, int bo) {
        const int at = abs_tile_of(t);
        const char* kp = kbase + (size_t)at * 131072;
        const char* vp = vbase + (size_t)at * 128;
        char* dK = smem + bo + wave * 1024;          // K region [bo, bo+8192)
        char* dV = dK + 8192;                         // V region [bo+8192, +8192)
        #pragma unroll
        for (int i = 0; i < 4; ++i)
            gload16(kp + ko + (size_t)i * 32768, dK + i * 2048);
        #pragma unroll
        for (int i = 0; i < 4; ++i)
            gload16(vp + vo + (size_t)i * 131072, dV + i * 2048);
    };

    // tile-invariant per-lane frag offsets within a region
    int qc[4];
    #pragma unroll
    for (int i = 0; i < 4; ++i)
        qc[i] = q32 * 128 + (((i * 2 + hi) ^ (q32 & 7)) << 4);

    f32x16 zro;
    #pragma unroll
    for (int r = 0; r < 16; ++r) zro[r] = 0.f;
    f32x16 acc[2][2];
    acc[0][0] = zro; acc[0][1] = zro; acc[1][0] = zro; acc[1][1] = zro;
    float ps[2] = {0.f, 0.f};

    // One half-tile chunk: QK (8 mfma) -> exp2 -> pack -> PV (8 mfma).
    #define CHUNK(RB, HF, BIAS) do {                                               \
        f32x16 S_[2];                                                              \
        {                                                                          \
            __builtin_amdgcn_s_setprio(1);                                         \
            bf16x8 f0 = *(const bf16x8*)(smem + (RB) + (HF)*4096 + qc[0]);         \
            bf16x8 f1 = *(const bf16x8*)(smem + (RB) + (HF)*4096 + qc[1]);         \
            bf16x8 f2 = *(const bf16x8*)(smem + (RB) + (HF)*4096 + qc[2]);         \
            bf16x8 f3 = *(const bf16x8*)(smem + (RB) + (HF)*4096 + qc[3]);         \
            _Pragma("unroll")                                                      \
            for (int qs = 0; qs < 2; ++qs) {                                       \
                f32x16 a = __builtin_amdgcn_mfma_f32_32x32x16_bf16(f0, qv[qs][0], zro, 0,0,0); \
                a = __builtin_amdgcn_mfma_f32_32x32x16_bf16(f1, qv[qs][1], a, 0,0,0); \
                a = __builtin_amdgcn_mfma_f32_32x32x16_bf16(f2, qv[qs][2], a, 0,0,0); \
                a = __builtin_amdgcn_mfma_f32_32x32x16_bf16(f3, qv[qs][3], a, 0,0,0); \
                S_[qs] = a;                                                        \
            }                                                                      \
            __builtin_amdgcn_s_setprio(0);                                         \
        }                                                                          \
        _Pragma("unroll")                                                          \
        for (int qs = 0; qs < 2; ++qs) {                                           \
            _Pragma("unroll")                                                      \
            for (int r = 0; r < 16; ++r)                                           \
                S_[qs][r] = exp2_fast(S_[qs][r] + (BIAS));                         \
            float s0 = (S_[qs][0] + S_[qs][1]) + (S_[qs][2] + S_[qs][3]);          \
            float s1 = (S_[qs][4] + S_[qs][5]) + (S_[qs][6] + S_[qs][7]);          \
            float s2 = (S_[qs][8] + S_[qs][9]) + (S_[qs][10] + S_[qs][11]);        \
            float s3 = (S_[qs][12] + S_[qs][13]) + (S_[qs][14] + S_[qs][15]);      \
            ps[qs] += (s0 + s1) + (s2 + s3);                                       \
        }                                                                          \
        bf16x8 pf0_[2], pf1_[2];                                                   \
        _Pragma("unroll")                                                          \
        for (int qs = 0; qs < 2; ++qs) {                                           \
            i32x4 u;                                                               \
            u[0] = (int)cvt_pk_bf16(S_[qs][0],  S_[qs][1]);                        \
            u[1] = (int)cvt_pk_bf16(S_[qs][2],  S_[qs][3]);                        \
            u[2] = (int)cvt_pk_bf16(S_[qs][4],  S_[qs][5]);                        \
            u[3] = (int)cvt_pk_bf16(S_[qs][6],  S_[qs][7]);                        \
            pf0_[qs] = __builtin_bit_cast(bf16x8, u);                              \
            u[0] = (int)cvt_pk_bf16(S_[qs][8],  S_[qs][9]);                        \
            u[1] = (int)cvt_pk_bf16(S_[qs][10], S_[qs][11]);                       \
            u[2] = (int)cvt_pk_bf16(S_[qs][12], S_[qs][13]);                       \
            u[3] = (int)cvt_pk_bf16(S_[qs][14], S_[qs][15]);                       \
            pf1_[qs] = __builtin_bit_cast(bf16x8, u);                              \
        }                                                                          \
        {                                                                          \
            __builtin_amdgcn_s_setprio(1);                                         \
            bf16x8 w00 = *(const bf16x8*)(smem + (RB) + 8192  + qc[2*(HF)]);       \
            bf16x8 w01 = *(const bf16x8*)(smem + (RB) + 8192  + qc[2*(HF)+1]);     \
            bf16x8 w10 = *(const bf16x8*)(smem + (RB) + 12288 + qc[2*(HF)]);       \
            bf16x8 w11 = *(const bf16x8*)(smem + (RB) + 12288 + qc[2*(HF)+1]);     \
            _Pragma("unroll")                                                      \
            for (int qs = 0; qs < 2; ++qs) {                                       \
                acc[qs][0] = __builtin_amdgcn_mfma_f32_32x32x16_bf16(w00, pf0_[qs], acc[qs][0], 0,0,0); \
                acc[qs][0] = __builtin_amdgcn_mfma_f32_32x32x16_bf16(w01, pf1_[qs], acc[qs][0], 0,0,0); \
                acc[qs][1] = __builtin_amdgcn_mfma_f32_32x32x16_bf16(w10, pf0_[qs], acc[qs][1], 0,0,0); \
                acc[qs][1] = __builtin_amdgcn_mfma_f32_32x32x16_bf16(w11, pf1_[qs], acc[qs][1], 0,0,0); \
            }                                                                      \
            __builtin_amdgcn_s_setprio(0);                                         \
        }                                                                          \
    } while (0)

    #define BARRIER() do {                                                         \
        __builtin_amdgcn_sched_barrier(0);                                         \
        __builtin_amdgcn_s_barrier();                                              \
        __builtin_amdgcn_sched_barrier(0);                                         \
    } while (0)

    // ---- prologue: stage tile 0; FULL drain (order-robust)
    stage(0, 0);
    asm volatile("s_waitcnt vmcnt(0)" ::: "memory");
    BARRIER();

    // ---- main loop (R5 protocol, 8 loads/iter): iter t stages t+1, computes t
    int bufo = 0;
    for (int t = 0; t < NT; ++t) {
        if (t + 1 < NT) {
            stage(t + 1, bufo ^ 16384);
            asm volatile("s_waitcnt vmcnt(8)" ::: "memory");   // tile t resident
        } else {
            asm volatile("s_waitcnt vmcnt(0)" ::: "memory");
        }
        BARRIER();
        const float bias = (t == 0) ? 1.0f : 0.0f;   // tile 0 weight 2
        CHUNK(bufo, 0, bias);
        CHUNK(bufo, 1, bias);
        BARRIER();
        bufo ^= 16384;
    }

    // ---- denominators + store
    #pragma unroll
    for (int qs = 0; qs < 2; ++qs) {
        float tot = ps[qs] + __shfl_xor(ps[qs], 32);
        float inv = 1.0f / tot;
        const size_t orow = (size_t)(b*S_TOT + s*L_ + qt*128 + wave*64 + qs*32 + q32);
        float* op = out + orow * HDIM + h * DH;
        #pragma unroll
        for (int m = 0; m < 4; ++m) {
            float4 w0, w1;
            w0.x = acc[qs][0][4*m+0]*inv; w0.y = acc[qs][0][4*m+1]*inv;
            w0.z = acc[qs][0][4*m+2]*inv; w0.w = acc[qs][0][4*m+3]*inv;
            *(float4*)(op + 8*m + 4*hi) = w0;
            w1.x = acc[qs][1][4*m+0]*inv; w1.y = acc[qs][1][4*m+1]*inv;
            w1.z = acc[qs][1][4*m+2]*inv; w1.w = acc[qs][1][4*m+3]*inv;
            *(float4*)(op + 32 + 8*m + 4*hi) = w1;
        }
    }
}

extern "C" void kernel_launch(void* const* d_in, const int* in_sizes, int n_in,
                              void* d_out, int out_size, void* d_ws, size_t ws_size,
                              hipStream_t stream) {
    const float* q = (const float*)d_in[0];
    const float* k = (const float*)d_in[1];
    const float* v = (const float*)d_in[2];
    char* ws = (char*)d_ws;
    short* kbuf = (short*)(ws);
    short* vbuf = (short*)(ws + (16u << 20));
    prep_kv<<<dim3(3072), dim3(256), 0, stream>>>(k, v, kbuf, vbuf);
    attn_kernel<<<dim3(1024), dim3(128), 0, stream>>>(q, kbuf, vbuf, (float*)d_out);
}

// Round 10
// 73.268 us; speedup vs baseline: 1.0380x; 1.0380x over previous
//
#include <hip/hip_runtime.h>
#include <hip/hip_bf16.h>

#define S_TOT 4096
#define HDIM  1024
#define NH    16
#define DH    64
#define L_    1024
#define NT    19   // 16 local + 3 distinct global tiles (shot-s global == local tile 0, weight 2)

using bf16x8 = __attribute__((ext_vector_type(8))) short;
using f32x16 = __attribute__((ext_vector_type(16))) float;
using i32x4  = __attribute__((ext_vector_type(4))) int;

typedef const __attribute__((address_space(1))) unsigned int* gp1_t;
typedef __attribute__((address_space(3))) unsigned int* lp3_t;

__device__ __forceinline__ short f2bf(float f) {
    union { float f; unsigned u; } x; x.f = f;
    unsigned r = x.u + 0x7FFFu + ((x.u >> 16) & 1u);
    return (short)(r >> 16);
}

__device__ __forceinline__ unsigned cvt_pk_bf16(float lo, float hi) {
    unsigned r;
    asm("v_cvt_pk_bf16_f32 %0, %1, %2" : "=v"(r) : "v"(lo), "v"(hi));
    return r;
}

__device__ __forceinline__ float exp2_fast(float x) {
#if __has_builtin(__builtin_amdgcn_exp2f)
    return __builtin_amdgcn_exp2f(x);
#else
    return exp2f(x);
#endif
}

__device__ __forceinline__ void gload16(const void* g, void* l) {
    __builtin_amdgcn_global_load_lds((gp1_t)g, (lp3_t)(unsigned long)(l), 16, 0, 0);
}

// ---------------- prep: K convert (blocks 0..1023), V transpose (1024..3071) --
__global__ __launch_bounds__(256) void prep_kv(
    const float* __restrict__ kf, const float* __restrict__ vf,
    short* __restrict__ kb, short* __restrict__ vb)
{
    __shared__ short st[64 * 70];
    const int bid = blockIdx.x, tid = threadIdx.x;
    if (bid < 1024) {
        const int gid = bid * 256 + tid;
        #pragma unroll
        for (int it = 0; it < 2; ++it) {
            size_t e = ((size_t)gid + (size_t)it * 262144) * 16;
            #pragma unroll
            for (int half = 0; half < 2; ++half) {
                float4 a = *(const float4*)(kf + e + half * 8);
                float4 c = *(const float4*)(kf + e + half * 8 + 4);
                bf16x8 r;
                r[0]=f2bf(a.x); r[1]=f2bf(a.y); r[2]=f2bf(a.z); r[3]=f2bf(a.w);
                r[4]=f2bf(c.x); r[5]=f2bf(c.y); r[6]=f2bf(c.z); r[7]=f2bf(c.w);
                *(bf16x8*)(kb + e + half * 8) = r;
            }
        }
    } else {
        const int vbid = bid - 1024;
        const int stile = vbid & 63, ht = (vbid >> 6) & 15, b = vbid >> 10;
        const int rt = tid >> 2, q4 = tid & 3;
        const float* src = vf + ((size_t)(b * S_TOT + stile * 64 + rt)) * HDIM + ht * 64 + q4 * 16;
        short* dst = st + rt * 70 + q4 * 16;
        #pragma unroll
        for (int i = 0; i < 4; ++i) {
            float4 x = *(const float4*)(src + i * 4);
            dst[i*4+0] = f2bf(x.x); dst[i*4+1] = f2bf(x.y);
            dst[i*4+2] = f2bf(x.z); dst[i*4+3] = f2bf(x.w);
        }
        __syncthreads();
        const int orow = tid >> 2, oq = tid & 3;
        bf16x8 o0, o1;
        #pragma unroll
        for (int j = 0; j < 8; ++j) o0[j] = st[(oq * 16 + j) * 70 + orow];
        #pragma unroll
        for (int j = 0; j < 8; ++j) o1[j] = st[(oq * 16 + 8 + j) * 70 + orow];
        short* dst2 = vb + ((size_t)((b * NH + ht) * 64 + orow)) * S_TOT + stile * 64 + oq * 16;
        *(bf16x8*)dst2 = o0;
        *(bf16x8*)(dst2 + 8) = o1;
    }
}

// ---------------- attention: R4 structure (8 waves x 32q, grid 512), 19 tiles,
// 3 LDS buffers -> single barrier per tile.
// Buffer regions (16KB each: K 8KB | V 8KB): B0@0, B1@16384, B2@32768.
// iter t: BARRIER; stage(t+2 -> buf[(t+2)%3]); compute(t from buf[t%3]);
//         vmcnt(2) (own-wave tile-t+1 loads done).
// Safety: barrier releases only after all waves finished iter t-1 reads of
// buf[(t-1)%3] == buf[(t+2)%3]; residency of tile t ensured by iter t-1's
// vmcnt(2) + this barrier.
__global__ __launch_bounds__(512, 2) void attn_kernel(
    const float* __restrict__ qf, const short* __restrict__ kb,
    const short* __restrict__ vb, float* __restrict__ out)
{
    __shared__ __align__(16) char smem[49152];
    const int tid  = threadIdx.x;
    const int wave = tid >> 6, lane = tid & 63;
    const int hi   = lane >> 5, q32 = lane & 31;

    // bijective XCD swizzle (512 % 8 == 0)
    const int bidhw = blockIdx.x;
    const int bid = ((bidhw & 7) << 6) | (bidhw >> 3);
    const int qt = bid & 3, h = (bid >> 2) & 15, s = (bid >> 6) & 3, b = bid >> 8;

    // ---- Q B-frags: lane holds Q[q=q32][d = dstep*16 + hi*8 + j] (scale folded)
    const float CSC = 0.125f * 1.4426950408889634f;
    const float* qp = qf + ((size_t)(b*S_TOT + s*L_ + qt*256 + wave*32 + q32)) * HDIM
                         + h * DH + hi * 8;
    bf16x8 qv[4];
    #pragma unroll
    for (int d = 0; d < 4; ++d) {
        float4 x0 = *(const float4*)(qp + d * 16);
        float4 x1 = *(const float4*)(qp + d * 16 + 4);
        i32x4 u;
        u[0] = (int)cvt_pk_bf16(x0.x * CSC, x0.y * CSC);
        u[1] = (int)cvt_pk_bf16(x0.z * CSC, x0.w * CSC);
        u[2] = (int)cvt_pk_bf16(x1.x * CSC, x1.y * CSC);
        u[3] = (int)cvt_pk_bf16(x1.z * CSC, x1.w * CSC);
        qv[d] = __builtin_bit_cast(bf16x8, u);
    }

    // ---- staging source offsets (chunk swizzle + K row bit2<->3 permute on
    // GLOBAL side, LDS dest linear). 512 lanes x 1 K-chunk + 1 V-chunk.
    const int cid = wave * 64 + lane;
    const int row = cid >> 3;
    const int lch = (cid & 7) ^ (row & 7);
    const int krow = (row & 0x33) | ((row & 4) << 1) | ((row & 8) >> 1);
    const size_t ko = (size_t)krow * 2048 + (lch << 4);
    const size_t vo = (size_t)row  * 8192 + (lch << 4);
    const char* kbase = (const char*)kb + ((size_t)b * S_TOT) * 2048 + h * 128;
    const char* vbase = (const char*)vb + ((size_t)(b * NH + h)) * (64ull * 8192);

    auto abs_tile_of = [&](int t) -> int {
        if (t < 16) return s * 16 + t;
        int g = t - 16; if (g >= s) ++g;   // skip duplicated shot-s global tile
        return g * 16;
    };
    auto stage = [&](int t, int bo) {
        const int at = abs_tile_of(t);
        const char* kp = kbase + (size_t)at * 131072;
        const char* vp = vbase + (size_t)at * 128;
        char* dK = smem + bo + wave * 1024;
        gload16(kp + ko, dK);            // K region [bo, bo+8192)
        gload16(vp + vo, dK + 8192);     // V region [bo+8192, bo+16384)
    };

    // tile-invariant per-lane frag offsets (row q32, chunk (2i+hi)^(q32&7))
    int qc[4];
    #pragma unroll
    for (int i = 0; i < 4; ++i)
        qc[i] = q32 * 128 + (((i * 2 + hi) ^ (q32 & 7)) << 4);

    f32x16 zro;
    #pragma unroll
    for (int r = 0; r < 16; ++r) zro[r] = 0.f;
    f32x16 acc0 = zro, acc1 = zro;   // O^T[dsub][q]
    float ps = 0.f;

    // ---- prologue: stage tiles 0,1; full drain (order-robust)
    stage(0, 0);
    stage(1, 16384);
    asm volatile("s_waitcnt vmcnt(0)" ::: "memory");

    int rd = 0, nx = 16384, st = 32768;   // buf[t%3], buf[(t+1)%3], buf[(t+2)%3]
    for (int t = 0; t < NT; ++t) {
        __builtin_amdgcn_sched_barrier(0);
        __builtin_amdgcn_s_barrier();
        __builtin_amdgcn_sched_barrier(0);

        if (t + 2 < NT) stage(t + 2, st);

        const float bias = (t == 0) ? 1.0f : 0.0f;   // tile 0 counted twice
        const char* sb = smem + rd;

        // ---- QK^T: sA = k rows [0,32), sB = [32,64) (permuted order)
        f32x16 sA, sB;
        {
            __builtin_amdgcn_s_setprio(1);
            bf16x8 a0 = *(const bf16x8*)(sb + qc[0]);
            bf16x8 b0 = *(const bf16x8*)(sb + 4096 + qc[0]);
            sA = __builtin_amdgcn_mfma_f32_32x32x16_bf16(a0, qv[0], zro, 0,0,0);
            sB = __builtin_amdgcn_mfma_f32_32x32x16_bf16(b0, qv[0], zro, 0,0,0);
            bf16x8 a1 = *(const bf16x8*)(sb + qc[1]);
            bf16x8 b1 = *(const bf16x8*)(sb + 4096 + qc[1]);
            sA = __builtin_amdgcn_mfma_f32_32x32x16_bf16(a1, qv[1], sA, 0,0,0);
            sB = __builtin_amdgcn_mfma_f32_32x32x16_bf16(b1, qv[1], sB, 0,0,0);
            bf16x8 a2 = *(const bf16x8*)(sb + qc[2]);
            bf16x8 b2 = *(const bf16x8*)(sb + 4096 + qc[2]);
            sA = __builtin_amdgcn_mfma_f32_32x32x16_bf16(a2, qv[2], sA, 0,0,0);
            sB = __builtin_amdgcn_mfma_f32_32x32x16_bf16(b2, qv[2], sB, 0,0,0);
            bf16x8 a3 = *(const bf16x8*)(sb + qc[3]);
            bf16x8 b3 = *(const bf16x8*)(sb + 4096 + qc[3]);
            sA = __builtin_amdgcn_mfma_f32_32x32x16_bf16(a3, qv[3], sA, 0,0,0);
            sB = __builtin_amdgcn_mfma_f32_32x32x16_bf16(b3, qv[3], sB, 0,0,0);
            __builtin_amdgcn_s_setprio(0);
        }

        // ---- no-max softmax (exp2 domain; fp32 accumulate of denominator)
        #pragma unroll
        for (int r = 0; r < 16; ++r) { float p = exp2_fast(sA[r] + bias); sA[r] = p; ps += p; }
        #pragma unroll
        for (int r = 0; r < 16; ++r) { float p = exp2_fast(sB[r] + bias); sB[r] = p; ps += p; }

        // ---- pack P into PV B-frags (in-lane; k-order matches via row permute)
        bf16x8 pf0, pf1, pf2, pf3;
        {
            i32x4 u;
            u[0]=(int)cvt_pk_bf16(sA[0],sA[1]);  u[1]=(int)cvt_pk_bf16(sA[2],sA[3]);
            u[2]=(int)cvt_pk_bf16(sA[4],sA[5]);  u[3]=(int)cvt_pk_bf16(sA[6],sA[7]);
            pf0 = __builtin_bit_cast(bf16x8, u);
            u[0]=(int)cvt_pk_bf16(sA[8],sA[9]);  u[1]=(int)cvt_pk_bf16(sA[10],sA[11]);
            u[2]=(int)cvt_pk_bf16(sA[12],sA[13]);u[3]=(int)cvt_pk_bf16(sA[14],sA[15]);
            pf1 = __builtin_bit_cast(bf16x8, u);
            u[0]=(int)cvt_pk_bf16(sB[0],sB[1]);  u[1]=(int)cvt_pk_bf16(sB[2],sB[3]);
            u[2]=(int)cvt_pk_bf16(sB[4],sB[5]);  u[3]=(int)cvt_pk_bf16(sB[6],sB[7]);
            pf2 = __builtin_bit_cast(bf16x8, u);
            u[0]=(int)cvt_pk_bf16(sB[8],sB[9]);  u[1]=(int)cvt_pk_bf16(sB[10],sB[11]);
            u[2]=(int)cvt_pk_bf16(sB[12],sB[13]);u[3]=(int)cvt_pk_bf16(sB[14],sB[15]);
            pf3 = __builtin_bit_cast(bf16x8, u);
        }

        // ---- PV: acc[dsub] += mfma(V^T frag, P frag) over 4 k-steps
        {
            __builtin_amdgcn_s_setprio(1);
            bf16x8 v00 = *(const bf16x8*)(sb + 8192  + qc[0]);
            bf16x8 v10 = *(const bf16x8*)(sb + 12288 + qc[0]);
            acc0 = __builtin_amdgcn_mfma_f32_32x32x16_bf16(v00, pf0, acc0, 0,0,0);
            acc1 = __builtin_amdgcn_mfma_f32_32x32x16_bf16(v10, pf0, acc1, 0,0,0);
            bf16x8 v01 = *(const bf16x8*)(sb + 8192  + qc[1]);
            bf16x8 v11 = *(const bf16x8*)(sb + 12288 + qc[1]);
            acc0 = __builtin_amdgcn_mfma_f32_32x32x16_bf16(v01, pf1, acc0, 0,0,0);
            acc1 = __builtin_amdgcn_mfma_f32_32x32x16_bf16(v11, pf1, acc1, 0,0,0);
            bf16x8 v02 = *(const bf16x8*)(sb + 8192  + qc[2]);
            bf16x8 v12 = *(const bf16x8*)(sb + 12288 + qc[2]);
            acc0 = __builtin_amdgcn_mfma_f32_32x32x16_bf16(v02, pf2, acc0, 0,0,0);
            acc1 = __builtin_amdgcn_mfma_f32_32x32x16_bf16(v12, pf2, acc1, 0,0,0);
            bf16x8 v03 = *(const bf16x8*)(sb + 8192  + qc[3]);
            bf16x8 v13 = *(const bf16x8*)(sb + 12288 + qc[3]);
            acc0 = __builtin_amdgcn_mfma_f32_32x32x16_bf16(v03, pf3, acc0, 0,0,0);
            acc1 = __builtin_amdgcn_mfma_f32_32x32x16_bf16(v13, pf3, acc1, 0,0,0);
            __builtin_amdgcn_s_setprio(0);
        }

        // own-wave wait: tile t+1 loads complete before next iteration's compute
        if (t + 1 < NT) {
            if (t + 2 < NT) { asm volatile("s_waitcnt vmcnt(2)" ::: "memory"); }
            else            { asm volatile("s_waitcnt vmcnt(0)" ::: "memory"); }
        }
        // rotate buffers
        int tmp = rd; rd = nx; nx = st; st = tmp;
    }

    // ---- epilogue: denominator across hi halves, store O^T slices as float4
    float tot = ps + __shfl_xor(ps, 32);
    float inv = 1.0f / tot;
    const size_t orow = (size_t)(b*S_TOT + s*L_ + qt*256 + wave*32 + q32);
    float* op = out + orow * HDIM + h * DH;
    #pragma unroll
    for (int m = 0; m < 4; ++m) {
        float4 w0, w1;
        w0.x = acc0[4*m+0]*inv; w0.y = acc0[4*m+1]*inv;
        w0.z = acc0[4*m+2]*inv; w0.w = acc0[4*m+3]*inv;
        *(float4*)(op + 8*m + 4*hi) = w0;
        w1.x = acc1[4*m+0]*inv; w1.y = acc1[4*m+1]*inv;
        w1.z = acc1[4*m+2]*inv; w1.w = acc1[4*m+3]*inv;
        *(float4*)(op + 32 + 8*m + 4*hi) = w1;
    }
}

extern "C" void kernel_launch(void* const* d_in, const int* in_sizes, int n_in,
                              void* d_out, int out_size, void* d_ws, size_t ws_size,
                              hipStream_t stream) {
    const float* q = (const float*)d_in[0];
    const float* k = (const float*)d_in[1];
    const float* v = (const float*)d_in[2];
    char* ws = (char*)d_ws;
    short* kbuf = (short*)(ws);
    short* vbuf = (short*)(ws + (16u << 20));
    prep_kv<<<dim3(3072), dim3(256), 0, stream>>>(k, v, kbuf, vbuf);
    attn_kernel<<<dim3(512), dim3(512), 0, stream>>>(q, kbuf, vbuf, (float*)d_out);
}